// Round 7
// baseline (142.197 us; speedup 1.0000x reference)
//
#include <hip/hip_runtime.h>
#include <math.h>

namespace {
constexpr int Bn = 2, CF = 64;
constexpr int H = 256, W = 256, HW = H * W;
constexpr int IH = 512, IW = 512;

// ws layout in floats
constexpr int OFF_MT   = 0;                        // Mt[y][x], 256*256
constexpr int OFF_GXX  = OFF_MT + 256 * 256;       // [3][256] j-major
constexpr int OFF_GYY  = OFF_GXX + 3 * 256;        // [3][256]
constexpr int OFF_G    = OFF_GYY + 3 * 256;        // 3x3 = w_img^T w_img (pad 16)
constexpr int OFF_RIMG = OFF_G + 16;               // [b][c3][HW]
constexpr int OFF_S    = OFF_RIMG + Bn * 3 * HW;   // Bn*HW
// total ~= 591k floats (~2.4 MB)
}

// ---------------------------------------------------------------------------
// pos_kernel (fused pxy+gram): each block rebuilds PX/PY in LDS (cheap),
// then emits one Mt row: Mt[y=blk][x=t] = dot_o(PX[:,x], PY[:,y]).
// Block 0 also emits GXX/GYY (j-major) and G = w_img^T w_img.
// ---------------------------------------------------------------------------
__global__ __launch_bounds__(256) void pos_kernel(
    const float* __restrict__ w_pos, const float* __restrict__ w_img,
    float* __restrict__ Mt, float* __restrict__ GXX, float* __restrict__ GYY,
    float* __restrict__ G)
{
  __shared__ float PX[32][256];
  __shared__ float PY[32][256];
  const int t = threadIdx.x;
  const int blk = blockIdx.x;

  float s[16], c[16];
#pragma unroll
  for (int i = 0; i < 16; i++) {
    float d = expf((float)(2 * i) * (-0.2878231366242557f)); // -ln(1e4)/32
    float a = (float)t * d;
    s[i] = sinf(a);
    c[i] = cosf(a);
  }
#pragma unroll 4
  for (int o = 0; o < 32; o++) {
    const float* wr = w_pos + o * 64;
    float ax = 0.f, ay = 0.f;
#pragma unroll
    for (int i = 0; i < 16; i++) {
      ax += wr[2 * i] * s[i] + wr[2 * i + 1] * c[i];
      ay += wr[32 + 2 * i] * s[i] + wr[33 + 2 * i] * c[i];
    }
    PX[o][t] = ax;
    PY[o][t] = ay;
  }
  __syncthreads();

  float m = 0.f;
#pragma unroll
  for (int o = 0; o < 32; o++) m += PX[o][t] * PY[o][blk];
  Mt[blk * 256 + t] = m;

  if (blk == 0) {
#pragma unroll
    for (int j = 0; j < 3; j++) {
      const int nb = t + 2 * (j - 1);
      float gx = 0.f, gy = 0.f;
      if (nb >= 0 && nb < 256) {
#pragma unroll
        for (int o = 0; o < 32; o++) {
          gx += PX[o][t] * PX[o][nb];
          gy += PY[o][t] * PY[o][nb];
        }
      }
      GXX[j * 256 + t] = gx;
      GYY[j * 256 + t] = gy;
    }
    if (t < 9) {
      const int i = t / 3, j = t % 3;
      float g = 0.f;
#pragma unroll
      for (int o = 0; o < 32; o++) g += w_img[o * 3 + i] * w_img[o * 3 + j];
      G[t] = g;
    }
  }
}

// ---------------------------------------------------------------------------
// rimg: antialiased 2x bilinear downsample of img -> [b][c][HW].
// ---------------------------------------------------------------------------
__device__ __forceinline__ void resize_taps(int p, int n, float w[4], int idx[4])
{
#pragma unroll
  for (int r = 0; r < 4; r++) {
    int q = 2 * p - 1 + r;
    idx[r] = min(max(q, 0), 2 * n - 1);
  }
  if (p == 0)          { w[0] = 0.f;        w[1] = 3.f / 7.f; w[2] = 3.f / 7.f; w[3] = 1.f / 7.f; }
  else if (p == n - 1) { w[0] = 1.f / 7.f;  w[1] = 3.f / 7.f; w[2] = 3.f / 7.f; w[3] = 0.f; }
  else                 { w[0] = 0.125f;     w[1] = 0.375f;    w[2] = 0.375f;    w[3] = 0.125f; }
}

__global__ __launch_bounds__(256) void rimg_kernel(
    const float* __restrict__ img, float* __restrict__ rimg)
{
  const int p = blockIdx.x * 256 + threadIdx.x;
  const int c = blockIdx.y;
  const int b = blockIdx.z;
  const int x = p & (W - 1);
  const int y = p >> 8;

  float wy[4], wx[4];
  int ry[4], rx[4];
  resize_taps(y, H, wy, ry);
  resize_taps(x, W, wx, rx);

  const float* ip = img + ((size_t)(b * 3 + c) * IH) * IW;
  float acc = 0.f;
#pragma unroll
  for (int r = 0; r < 4; r++) {
    const float* rowp = ip + ry[r] * IW;
    float rs = wx[0] * rowp[rx[0]] + wx[1] * rowp[rx[1]] +
               wx[2] * rowp[rx[2]] + wx[3] * rowp[rx[3]];
    acc += wy[r] * rs;
  }
  rimg[((size_t)(b * 3 + c)) * HW + p] = acc;
}

// ---------------------------------------------------------------------------
// smap[b][p] = dot_c(inp[b,:,p], w_comp). 64 pix x 4 ch-groups, LDS reduce.
// ---------------------------------------------------------------------------
__global__ __launch_bounds__(256) void smap_kernel(
    const float* __restrict__ inp, const float* __restrict__ w_comp,
    float* __restrict__ smap)
{
  __shared__ float red[256];
  const int lane = threadIdx.x & 63;
  const int cg = threadIdx.x >> 6;         // 0..3
  const int p = blockIdx.x * 64 + lane;
  const int b = blockIdx.z;

  const float* ib = inp + (size_t)b * CF * HW + (size_t)cg * 16 * HW + p;
  float a0 = 0.f, a1 = 0.f, a2 = 0.f, a3 = 0.f;
#pragma unroll
  for (int c = 0; c < 16; c += 4) {
    a0 += ib[(size_t)(c + 0) * HW] * w_comp[cg * 16 + c + 0];
    a1 += ib[(size_t)(c + 1) * HW] * w_comp[cg * 16 + c + 1];
    a2 += ib[(size_t)(c + 2) * HW] * w_comp[cg * 16 + c + 2];
    a3 += ib[(size_t)(c + 3) * HW] * w_comp[cg * 16 + c + 3];
  }
  red[threadIdx.x] = (a0 + a1) + (a2 + a3);
  __syncthreads();
  if (threadIdx.x < 64) {
    smap[(size_t)b * HW + blockIdx.x * 64 + threadIdx.x] =
        red[threadIdx.x] + red[threadIdx.x + 64] +
        red[threadIdx.x + 128] + red[threadIdx.x + 192];
  }
}

// ---------------------------------------------------------------------------
// phigather (fused): per thread (cg of 16 channels, pixel, b):
//  phase 1: phi[k] = valid_k * sigmoid(smap[nb_k]) *
//           ( rimg[p]^T G rimg[nb_k] + GXX[kx][x] + GYY[ky][y]
//             + Mt[y][cx] + Mt[cy][x] )            (registers only)
//  phase 2: out[c][p] = sum_k phi[k] * inp[c][nb_k] for 16 channels.
// phi recomputed once per cg (4x); inputs are L2-resident. No phi buffer.
// ---------------------------------------------------------------------------
__global__ __launch_bounds__(256) void phigather_kernel(
    const float* __restrict__ inp, const float* __restrict__ rimg,
    const float* __restrict__ smap, const float* __restrict__ Mt,
    const float* __restrict__ GXX, const float* __restrict__ GYY,
    const float* __restrict__ G, float* __restrict__ out)
{
  const int cg = blockIdx.x;               // 0..3, channels 16*cg..16*cg+15
  const int p = blockIdx.y * 256 + threadIdx.x;
  const int b = blockIdx.z;
  const int x = p & (W - 1);
  const int y = p >> 8;

  const float* rb = rimg + (size_t)b * 3 * HW;
  const float r0 = rb[p], r1 = rb[HW + p], r2 = rb[2 * HW + p];
  const float g0 = G[0], g1 = G[1], g2 = G[2];
  const float g3 = G[3], g4 = G[4], g5 = G[5];
  const float g6 = G[6], g7 = G[7], g8 = G[8];
  const float* sb = smap + (size_t)b * HW;

  float ph[9];
  int nb[9];
#pragma unroll
  for (int k = 0; k < 9; k++) {
    const int ky = k / 3, kx = k % 3;
    const int ny = y + 2 * (ky - 1), nx = x + 2 * (kx - 1);
    const bool valid = ((unsigned)ny < (unsigned)H) & ((unsigned)nx < (unsigned)W);
    const int cy = min(max(ny, 0), H - 1);
    const int cx = min(max(nx, 0), W - 1);
    const int np = cy * W + cx;
    nb[k] = np;

    const float n0 = rb[np], n1 = rb[HW + np], n2 = rb[2 * HW + np];
    float fs = r0 * (g0 * n0 + g1 * n1 + g2 * n2)
             + r1 * (g3 * n0 + g4 * n1 + g5 * n2)
             + r2 * (g6 * n0 + g7 * n1 + g8 * n2);
    fs += GXX[kx * 256 + x] + GYY[ky * 256 + y]
        + Mt[y * 256 + cx] + Mt[cy * 256 + x];

    const float s = sb[np];
    const float cs = 1.f / (1.f + expf(-s));
    ph[k] = valid ? cs * fs : 0.f;
  }

  const float* ib = inp + (size_t)b * CF * HW + (size_t)cg * 16 * HW;
  float* ob = out + (size_t)b * CF * HW + (size_t)cg * 16 * HW;
#pragma unroll 4
  for (int c = 0; c < 16; c++) {
    const float* ic = ib + (size_t)c * HW;
    float acc = ph[0] * ic[nb[0]];
#pragma unroll
    for (int k = 1; k < 9; k++) acc += ph[k] * ic[nb[k]];
    ob[(size_t)c * HW + p] = acc;
  }
}

// ---------------------------------------------------------------------------
extern "C" void kernel_launch(void* const* d_in, const int* in_sizes, int n_in,
                              void* d_out, int out_size, void* d_ws, size_t ws_size,
                              hipStream_t stream)
{
  const float* inp    = (const float*)d_in[0];
  const float* img    = (const float*)d_in[1];
  const float* w_pos  = (const float*)d_in[2];
  const float* w_img  = (const float*)d_in[3];
  const float* w_comp = (const float*)d_in[4];
  float* out = (float*)d_out;
  float* ws  = (float*)d_ws;

  float* Mt   = ws + OFF_MT;
  float* GXX  = ws + OFF_GXX;
  float* GYY  = ws + OFF_GYY;
  float* G    = ws + OFF_G;
  float* rimg = ws + OFF_RIMG;
  float* smap = ws + OFF_S;

  hipLaunchKernelGGL(pos_kernel, dim3(256), dim3(256), 0, stream,
                     w_pos, w_img, Mt, GXX, GYY, G);

  hipLaunchKernelGGL(rimg_kernel, dim3(HW / 256, 3, Bn), dim3(256), 0, stream,
                     img, rimg);
  hipLaunchKernelGGL(smap_kernel, dim3(HW / 64, 1, Bn), dim3(256), 0, stream,
                     inp, w_comp, smap);

  hipLaunchKernelGGL(phigather_kernel, dim3(CF / 16, HW / 256, Bn), dim3(256), 0, stream,
                     inp, rimg, smap, Mt, GXX, GYY, G, out);
}

// Round 8
// 123.178 us; speedup vs baseline: 1.1544x; 1.1544x over previous
//
#include <hip/hip_runtime.h>
#include <math.h>

namespace {
constexpr int Bn = 2, CF = 64;
constexpr int H = 256, W = 256, HW = H * W;
constexpr int IH = 512, IW = 512;

// ws layout in floats
constexpr int OFF_MT   = 0;                        // Mt[y][x], 256*256
constexpr int OFF_GXX  = OFF_MT + 256 * 256;       // [3][256] j-major
constexpr int OFF_GYY  = OFF_GXX + 3 * 256;        // [3][256]
constexpr int OFF_G    = OFF_GYY + 3 * 256;        // 3x3 = w_img^T w_img (pad 16)
constexpr int OFF_RIMG = OFF_G + 16;               // [b][c3][HW]
constexpr int OFF_S    = OFF_RIMG + Bn * 3 * HW;   // Bn*HW
// PX/PY (32*256 each) overlay the RIMG region: consumed by gram_kernel
// before rimg_kernel writes it (same stream => ordered).
constexpr int OFF_PX   = OFF_RIMG;
constexpr int OFF_PY   = OFF_RIMG + 32 * 256;
}

// ---------------------------------------------------------------------------
// P1: PX[o][t], PY[o][t] sinusoid projections. Transcendentals computed
// exactly 32x256 times total (NOT per-Mt-row — that was R7's 43us mistake).
// ---------------------------------------------------------------------------
__global__ __launch_bounds__(256) void pxy_kernel(
    const float* __restrict__ w_pos,
    float* __restrict__ PX, float* __restrict__ PY)
{
  const int t = threadIdx.x;
  const int o = blockIdx.x;
  float s[16], c[16];
#pragma unroll
  for (int i = 0; i < 16; i++) {
    float d = expf((float)(2 * i) * (-0.2878231366242557f)); // -ln(1e4)/32
    float a = (float)t * d;
    s[i] = sinf(a);
    c[i] = cosf(a);
  }
  const float* wr = w_pos + o * 64;
  float ax = 0.f, ay = 0.f;
#pragma unroll
  for (int i = 0; i < 16; i++) {
    ax += wr[2 * i] * s[i] + wr[2 * i + 1] * c[i];
    ay += wr[32 + 2 * i] * s[i] + wr[33 + 2 * i] * c[i];
  }
  PX[o * 256 + t] = ax;
  PY[o * 256 + t] = ay;
}

// ---------------------------------------------------------------------------
// P2: Mt[t][a] = dot_o(PX[:,a], PY[:,t]) (transposed: phigather reads
// coalesce). Block 0 also computes GXX/GYY (j-major) and G = w_img^T w_img.
// PX/PY are 64 KB total -> L2-resident across the 256 blocks.
// ---------------------------------------------------------------------------
__global__ __launch_bounds__(256) void gram_kernel(
    const float* __restrict__ PX, const float* __restrict__ PY,
    const float* __restrict__ w_img,
    float* __restrict__ Mt, float* __restrict__ GXX, float* __restrict__ GYY,
    float* __restrict__ G)
{
  const int a = threadIdx.x;
  const int t = blockIdx.x;

  float m = 0.f;
#pragma unroll
  for (int o = 0; o < 32; o++) m += PX[o * 256 + a] * PY[o * 256 + t];
  Mt[t * 256 + a] = m;

  if (t == 0) {
#pragma unroll
    for (int j = 0; j < 3; j++) {
      const int nb = a + 2 * (j - 1);
      float gx = 0.f, gy = 0.f;
      if (nb >= 0 && nb < 256) {
#pragma unroll
        for (int o = 0; o < 32; o++) {
          gx += PX[o * 256 + a] * PX[o * 256 + nb];
          gy += PY[o * 256 + a] * PY[o * 256 + nb];
        }
      }
      GXX[j * 256 + a] = gx;
      GYY[j * 256 + a] = gy;
    }
    if (a < 9) {
      const int i = a / 3, j = a % 3;
      float g = 0.f;
#pragma unroll
      for (int o = 0; o < 32; o++) g += w_img[o * 3 + i] * w_img[o * 3 + j];
      G[a] = g;
    }
  }
}

// ---------------------------------------------------------------------------
// rimg: antialiased 2x bilinear downsample of img -> [b][c][HW].
// ---------------------------------------------------------------------------
__device__ __forceinline__ void resize_taps(int p, int n, float w[4], int idx[4])
{
#pragma unroll
  for (int r = 0; r < 4; r++) {
    int q = 2 * p - 1 + r;
    idx[r] = min(max(q, 0), 2 * n - 1);
  }
  if (p == 0)          { w[0] = 0.f;        w[1] = 3.f / 7.f; w[2] = 3.f / 7.f; w[3] = 1.f / 7.f; }
  else if (p == n - 1) { w[0] = 1.f / 7.f;  w[1] = 3.f / 7.f; w[2] = 3.f / 7.f; w[3] = 0.f; }
  else                 { w[0] = 0.125f;     w[1] = 0.375f;    w[2] = 0.375f;    w[3] = 0.125f; }
}

__global__ __launch_bounds__(256) void rimg_kernel(
    const float* __restrict__ img, float* __restrict__ rimg)
{
  const int p = blockIdx.x * 256 + threadIdx.x;
  const int c = blockIdx.y;
  const int b = blockIdx.z;
  const int x = p & (W - 1);
  const int y = p >> 8;

  float wy[4], wx[4];
  int ry[4], rx[4];
  resize_taps(y, H, wy, ry);
  resize_taps(x, W, wx, rx);

  const float* ip = img + ((size_t)(b * 3 + c) * IH) * IW;
  float acc = 0.f;
#pragma unroll
  for (int r = 0; r < 4; r++) {
    const float* rowp = ip + ry[r] * IW;
    float rs = wx[0] * rowp[rx[0]] + wx[1] * rowp[rx[1]] +
               wx[2] * rowp[rx[2]] + wx[3] * rowp[rx[3]];
    acc += wy[r] * rs;
  }
  rimg[((size_t)(b * 3 + c)) * HW + p] = acc;
}

// ---------------------------------------------------------------------------
// smap[b][p] = dot_c(inp[b,:,p], w_comp). 64 pix x 4 ch-groups, LDS reduce.
// ---------------------------------------------------------------------------
__global__ __launch_bounds__(256) void smap_kernel(
    const float* __restrict__ inp, const float* __restrict__ w_comp,
    float* __restrict__ smap)
{
  __shared__ float red[256];
  const int lane = threadIdx.x & 63;
  const int cg = threadIdx.x >> 6;         // 0..3
  const int p = blockIdx.x * 64 + lane;
  const int b = blockIdx.z;

  const float* ib = inp + (size_t)b * CF * HW + (size_t)cg * 16 * HW + p;
  float a0 = 0.f, a1 = 0.f, a2 = 0.f, a3 = 0.f;
#pragma unroll
  for (int c = 0; c < 16; c += 4) {
    a0 += ib[(size_t)(c + 0) * HW] * w_comp[cg * 16 + c + 0];
    a1 += ib[(size_t)(c + 1) * HW] * w_comp[cg * 16 + c + 1];
    a2 += ib[(size_t)(c + 2) * HW] * w_comp[cg * 16 + c + 2];
    a3 += ib[(size_t)(c + 3) * HW] * w_comp[cg * 16 + c + 3];
  }
  red[threadIdx.x] = (a0 + a1) + (a2 + a3);
  __syncthreads();
  if (threadIdx.x < 64) {
    smap[(size_t)b * HW + blockIdx.x * 64 + threadIdx.x] =
        red[threadIdx.x] + red[threadIdx.x + 64] +
        red[threadIdx.x + 128] + red[threadIdx.x + 192];
  }
}

// ---------------------------------------------------------------------------
// phigather (fused): per thread (cg of 16 channels, pixel, b):
//  phase 1: phi[k] = valid_k * sigmoid(smap[nb_k]) *
//           ( rimg[p]^T G rimg[nb_k] + GXX[kx][x] + GYY[ky][y]
//             + Mt[y][cx] + Mt[cy][x] )            (registers only)
//  phase 2: out[c][p] = sum_k phi[k] * inp[c][nb_k] for 16 channels.
// phi recomputed once per cg (4x); those reads are L2-resident. No phi buf.
// ---------------------------------------------------------------------------
__global__ __launch_bounds__(256) void phigather_kernel(
    const float* __restrict__ inp, const float* __restrict__ rimg,
    const float* __restrict__ smap, const float* __restrict__ Mt,
    const float* __restrict__ GXX, const float* __restrict__ GYY,
    const float* __restrict__ G, float* __restrict__ out)
{
  const int cg = blockIdx.x;               // 0..3, channels 16*cg..16*cg+15
  const int p = blockIdx.y * 256 + threadIdx.x;
  const int b = blockIdx.z;
  const int x = p & (W - 1);
  const int y = p >> 8;

  const float* rb = rimg + (size_t)b * 3 * HW;
  const float r0 = rb[p], r1 = rb[HW + p], r2 = rb[2 * HW + p];
  const float g0 = G[0], g1 = G[1], g2 = G[2];
  const float g3 = G[3], g4 = G[4], g5 = G[5];
  const float g6 = G[6], g7 = G[7], g8 = G[8];
  const float* sb = smap + (size_t)b * HW;

  float ph[9];
  int nb[9];
#pragma unroll
  for (int k = 0; k < 9; k++) {
    const int ky = k / 3, kx = k % 3;
    const int ny = y + 2 * (ky - 1), nx = x + 2 * (kx - 1);
    const bool valid = ((unsigned)ny < (unsigned)H) & ((unsigned)nx < (unsigned)W);
    const int cy = min(max(ny, 0), H - 1);
    const int cx = min(max(nx, 0), W - 1);
    const int np = cy * W + cx;
    nb[k] = np;

    const float n0 = rb[np], n1 = rb[HW + np], n2 = rb[2 * HW + np];
    float fs = r0 * (g0 * n0 + g1 * n1 + g2 * n2)
             + r1 * (g3 * n0 + g4 * n1 + g5 * n2)
             + r2 * (g6 * n0 + g7 * n1 + g8 * n2);
    fs += GXX[kx * 256 + x] + GYY[ky * 256 + y]
        + Mt[y * 256 + cx] + Mt[cy * 256 + x];

    const float s = sb[np];
    const float cs = 1.f / (1.f + expf(-s));
    ph[k] = valid ? cs * fs : 0.f;
  }

  const float* ib = inp + (size_t)b * CF * HW + (size_t)cg * 16 * HW;
  float* ob = out + (size_t)b * CF * HW + (size_t)cg * 16 * HW;
#pragma unroll 4
  for (int c = 0; c < 16; c++) {
    const float* ic = ib + (size_t)c * HW;
    float acc = ph[0] * ic[nb[0]];
#pragma unroll
    for (int k = 1; k < 9; k++) acc += ph[k] * ic[nb[k]];
    ob[(size_t)c * HW + p] = acc;
  }
}

// ---------------------------------------------------------------------------
extern "C" void kernel_launch(void* const* d_in, const int* in_sizes, int n_in,
                              void* d_out, int out_size, void* d_ws, size_t ws_size,
                              hipStream_t stream)
{
  const float* inp    = (const float*)d_in[0];
  const float* img    = (const float*)d_in[1];
  const float* w_pos  = (const float*)d_in[2];
  const float* w_img  = (const float*)d_in[3];
  const float* w_comp = (const float*)d_in[4];
  float* out = (float*)d_out;
  float* ws  = (float*)d_ws;

  float* Mt   = ws + OFF_MT;
  float* GXX  = ws + OFF_GXX;
  float* GYY  = ws + OFF_GYY;
  float* G    = ws + OFF_G;
  float* rimg = ws + OFF_RIMG;
  float* smap = ws + OFF_S;
  float* PX   = ws + OFF_PX;   // overlays rimg (consumed before rimg written)
  float* PY   = ws + OFF_PY;

  hipLaunchKernelGGL(pxy_kernel, dim3(32), dim3(256), 0, stream, w_pos, PX, PY);
  hipLaunchKernelGGL(gram_kernel, dim3(256), dim3(256), 0, stream,
                     PX, PY, w_img, Mt, GXX, GYY, G);

  hipLaunchKernelGGL(rimg_kernel, dim3(HW / 256, 3, Bn), dim3(256), 0, stream,
                     img, rimg);
  hipLaunchKernelGGL(smap_kernel, dim3(HW / 64, 1, Bn), dim3(256), 0, stream,
                     inp, w_comp, smap);

  hipLaunchKernelGGL(phigather_kernel, dim3(CF / 16, HW / 256, Bn), dim3(256), 0, stream,
                     inp, rimg, smap, Mt, GXX, GYY, G, out);
}